// Round 3
// baseline (470.093 us; speedup 1.0000x reference)
//
#include <hip/hip_runtime.h>

#define NSTEPS 30
#define DIM 192
static constexpr long DHW = (long)DIM * DIM * DIM;
static constexpr int PTS_PER_WAVE = 21;   // 3 lanes per point, lane 63 idle
static constexpr int MAX_LDS_BINS = 2048;

// Cofactor 4x4 inverse in double — registers only.
__device__ __forceinline__ void invert4x4_one(const float* __restrict__ aff,
                                              float* __restrict__ out, int b) {
    double a[16];
#pragma unroll
    for (int i = 0; i < 16; i++) a[i] = (double)aff[b * 16 + i];
    double s0 = a[0]*a[5]  - a[4]*a[1];
    double s1 = a[0]*a[6]  - a[4]*a[2];
    double s2 = a[0]*a[7]  - a[4]*a[3];
    double s3 = a[1]*a[6]  - a[5]*a[2];
    double s4 = a[1]*a[7]  - a[5]*a[3];
    double s5 = a[2]*a[7]  - a[6]*a[3];
    double c5 = a[10]*a[15] - a[14]*a[11];
    double c4 = a[9]*a[15]  - a[13]*a[11];
    double c3 = a[9]*a[14]  - a[13]*a[10];
    double c2 = a[8]*a[15]  - a[12]*a[11];
    double c1 = a[8]*a[14]  - a[12]*a[10];
    double c0 = a[8]*a[13]  - a[12]*a[9];
    double det = s0*c5 - s1*c4 + s2*c3 + s3*c2 - s4*c1 + s5*c0;
    double inv = 1.0 / det;
    double o[16];
    o[0]  = ( a[5]*c5 - a[6]*c4 + a[7]*c3) * inv;
    o[1]  = (-a[1]*c5 + a[2]*c4 - a[3]*c3) * inv;
    o[2]  = ( a[13]*s5 - a[14]*s4 + a[15]*s3) * inv;
    o[3]  = (-a[9]*s5 + a[10]*s4 - a[11]*s3) * inv;
    o[4]  = (-a[4]*c5 + a[6]*c2 - a[7]*c1) * inv;
    o[5]  = ( a[0]*c5 - a[2]*c2 + a[3]*c1) * inv;
    o[6]  = (-a[12]*s5 + a[14]*s2 - a[15]*s1) * inv;
    o[7]  = ( a[8]*s5 - a[10]*s2 + a[11]*s1) * inv;
    o[8]  = ( a[4]*c4 - a[5]*c2 + a[7]*c0) * inv;
    o[9]  = (-a[0]*c4 + a[1]*c2 - a[3]*c0) * inv;
    o[10] = ( a[12]*s4 - a[13]*s2 + a[15]*s0) * inv;
    o[11] = (-a[8]*s4 + a[9]*s2 - a[11]*s0) * inv;
    o[12] = (-a[4]*c3 + a[5]*c1 - a[6]*c0) * inv;
    o[13] = ( a[0]*c3 - a[1]*c1 + a[2]*c0) * inv;
    o[14] = (-a[12]*s3 + a[13]*s1 - a[14]*s0) * inv;
    o[15] = ( a[8]*s3 - a[9]*s1 + a[10]*s0) * inv;
#pragma unroll
    for (int i = 0; i < 16; i++) out[b * 16 + i] = (float)o[i];
}

// Predicted d-slab bin of a point. MUST be bit-identical between hist and
// scatter (shared function => same codegen) or the bucket sort corrupts.
__device__ __forceinline__ int bin_of_point(const float* __restrict__ verts,
                                            const float* __restrict__ affine,
                                            int pt, int N) {
    int b = pt / N;
    const float* A = affine + b * 16;
    const float* v = verts + (size_t)pt * 3;
    float x = A[0] * v[0] + A[1] * v[1] + A[2] * v[2] + A[3];
    int d = (int)x;
    d = min(max(d, 0), DIM - 1);
    return b * DIM + d;
}

// Zero hist + compute affine inverse. One block, runs before hist_kernel.
__global__ void setup_kernel(const float* __restrict__ aff,
                             float* __restrict__ invaff,
                             int* __restrict__ hist, int NB, int B) {
    for (int i = threadIdx.x; i < NB; i += blockDim.x) hist[i] = 0;
    if (threadIdx.x < (unsigned)B) invert4x4_one(aff, invaff, (int)threadIdx.x);
}

__global__ __launch_bounds__(256) void hist_kernel(
    const float* __restrict__ verts, const float* __restrict__ affine,
    int* __restrict__ hist, int N, int B, int total) {
    __shared__ int lh[MAX_LDS_BINS];
    int NB = B * DIM;
    bool use_lds = (NB <= MAX_LDS_BINS);
    if (use_lds) {
        for (int i = threadIdx.x; i < NB; i += blockDim.x) lh[i] = 0;
        __syncthreads();
    }
    int stride = gridDim.x * blockDim.x;
    for (int pt = blockIdx.x * blockDim.x + threadIdx.x; pt < total; pt += stride) {
        int bin = bin_of_point(verts, affine, pt, N);
        if (use_lds) atomicAdd(&lh[bin], 1);
        else         atomicAdd(&hist[bin], 1);
    }
    if (use_lds) {
        __syncthreads();
        for (int i = threadIdx.x; i < NB; i += blockDim.x) {
            int c = lh[i];
            if (c) atomicAdd(&hist[i], c);
        }
    }
}

// Exclusive scan of hist -> cursors. One block; NB is tiny (B*192).
__global__ void scan_kernel(const int* __restrict__ hist,
                            int* __restrict__ cursors, int NB) {
    __shared__ int lh[MAX_LDS_BINS];
    if (NB <= MAX_LDS_BINS) {
        for (int i = threadIdx.x; i < NB; i += blockDim.x) lh[i] = hist[i];
        __syncthreads();
        if (threadIdx.x == 0) {
            int acc = 0;
            for (int i = 0; i < NB; i++) { int c = lh[i]; lh[i] = acc; acc += c; }
        }
        __syncthreads();
        for (int i = threadIdx.x; i < NB; i += blockDim.x) cursors[i] = lh[i];
    } else if (threadIdx.x == 0) {
        int acc = 0;
        for (int i = 0; i < NB; i++) { int c = hist[i]; cursors[i] = acc; acc += c; }
    }
}

__global__ __launch_bounds__(256) void scatter_kernel(
    const float* __restrict__ verts, const float* __restrict__ affine,
    int* __restrict__ cursors, int* __restrict__ order,
    int N, int B, int total) {
    int stride = gridDim.x * blockDim.x;
    for (int pt = blockIdx.x * blockDim.x + threadIdx.x; pt < total; pt += stride) {
        int bin = bin_of_point(verts, affine, pt, N);
        int idx = atomicAdd(&cursors[bin], 1);
        order[idx] = pt;
    }
}

// 3 lanes per point, f32 direct gathers from the channel-planar flow field.
// Points arrive slab-sorted via order[], so each wave's 21 points share one
// d-slab: the 0.44 MB slab working set is L2-resident and the 170 MB volume
// streams through HBM exactly once across the slab sweep.
__global__ __launch_bounds__(256) void deform_sorted_kernel(
    const float* __restrict__ verts,
    const float* __restrict__ affine,
    const float* __restrict__ flow,
    const float* __restrict__ invaff,
    const int*   __restrict__ order,
    float* __restrict__ out_pred,
    float* __restrict__ out_flow,
    int N, int B) {
    int lane = threadIdx.x & 63;
    int wib  = threadIdx.x >> 6;
    long gwave = (long)blockIdx.x * (blockDim.x >> 6) + wib;

    int piw = lane / 3;
    if (piw > PTS_PER_WAVE - 1) piw = PTS_PER_WAVE - 1;
    int ch = lane - piw * 3;
    if (ch > 2) ch = 2;

    long total = (long)B * N;
    long slot = gwave * PTS_PER_WAVE + piw;
    bool valid = (lane < 63) && (slot < total);
    long slotc = valid ? slot : (total - 1);
    // safety clamp: order[] should be a permutation, but never index OOB.
    long ptc = (long)min(max(order[slotc], 0), (int)(total - 1));
    int b = (int)(ptc / N);
    int n = (int)(ptc - (long)b * N);

    const float* A = affine + b * 16;
    const float* v = verts + (size_t)ptc * 3;
    float vx = v[0], vy = v[1], vz = v[2];
    float x = A[0] * vx + A[1] * vy + A[2]  * vz + A[3];
    float y = A[4] * vx + A[5] * vy + A[6]  * vz + A[7];
    float z = A[8] * vx + A[9] * vy + A[10] * vz + A[11];
    float p0 = (ch == 0) ? x : (ch == 1) ? y : z;

    const float* Fc = flow + ((size_t)b * 3 + ch) * (size_t)DHW;
    const float scale = (float)(1.0 / NSTEPS);

    float cc[8];
    int key = -1;
    int bl = piw * 3;

    for (int s = 0; s < NSTEPS; s++) {
        float pd = fminf(fmaxf(x, 0.0f), (float)(DIM - 1));
        float ph = fminf(fmaxf(y, 0.0f), (float)(DIM - 1));
        float pw = fminf(fmaxf(z, 0.0f), (float)(DIM - 1));
        float fd0 = floorf(pd), fh0 = floorf(ph), fw0 = floorf(pw);
        int d0 = (int)fd0, h0 = (int)fh0, w0 = (int)fw0;
        float fd = pd - fd0, fh = ph - fh0, fw = pw - fw0;

        int k = (d0 * DIM + h0) * DIM + w0;
        if (k != key) {
            key = k;
            int d1 = min(d0 + 1, DIM - 1);
            int h1 = min(h0 + 1, DIM - 1);
            int w1 = min(w0 + 1, DIM - 1);
            int r00 = (d0 * DIM + h0) * DIM;
            int r01 = (d0 * DIM + h1) * DIM;
            int r10 = (d1 * DIM + h0) * DIM;
            int r11 = (d1 * DIM + h1) * DIM;
            cc[0] = Fc[r00 + w0] * scale;
            cc[1] = Fc[r00 + w1] * scale;
            cc[2] = Fc[r01 + w0] * scale;
            cc[3] = Fc[r01 + w1] * scale;
            cc[4] = Fc[r10 + w0] * scale;
            cc[5] = Fc[r10 + w1] * scale;
            cc[6] = Fc[r11 + w0] * scale;
            cc[7] = Fc[r11 + w1] * scale;
        }

        float omfw = 1.0f - fw, omfh = 1.0f - fh, omfd = 1.0f - fd;
        float c00 = cc[0] * omfw + cc[1] * fw;
        float c01 = cc[2] * omfw + cc[3] * fw;
        float c10 = cc[4] * omfw + cc[5] * fw;
        float c11 = cc[6] * omfw + cc[7] * fw;
        float c0 = c00 * omfh + c01 * fh;
        float c1 = c10 * omfh + c11 * fh;
        float val = c0 * omfd + c1 * fd;

        float v0 = __shfl(val, bl,     64);
        float v1 = __shfl(val, bl + 1, 64);
        float v2 = __shfl(val, bl + 2, 64);
        x += v0; y += v1; z += v2;
    }

    if (valid) {
        float posc = (ch == 0) ? x : (ch == 1) ? y : z;
        float fint = posc - p0;
        const float* Ai = invaff + b * 16 + ch * 4;
        float o = Ai[0] * x + Ai[1] * y + Ai[2] * z + Ai[3];
        out_pred[(size_t)ptc * 3 + ch] = o;
        out_flow[(size_t)b * 3 * N + (size_t)ch * N + n] = fint;
    }
}

// Fallback: unsorted f32 direct-gather (used only if ws too small for sort).
__global__ __launch_bounds__(256) void deform_kernel(
    const float* __restrict__ verts,
    const float* __restrict__ affine,
    const float* __restrict__ flow,
    const float* __restrict__ invaff,
    float* __restrict__ out_pred,
    float* __restrict__ out_flow,
    int N, int B) {
    int lane = threadIdx.x & 63;
    int wib  = threadIdx.x >> 6;
    long gwave = (long)blockIdx.x * (blockDim.x >> 6) + wib;
    int piw = lane / 3;
    if (piw > PTS_PER_WAVE - 1) piw = PTS_PER_WAVE - 1;
    int ch = lane - piw * 3;
    if (ch > 2) ch = 2;
    long pt = gwave * PTS_PER_WAVE + piw;
    bool valid = (lane < 63) && (pt < (long)B * N);
    long ptc = valid ? pt : ((long)B * N - 1);
    int b = (int)(ptc / N);
    int n = (int)(ptc - (long)b * N);
    const float* A = affine + b * 16;
    const float* v = verts + (size_t)ptc * 3;
    float vx = v[0], vy = v[1], vz = v[2];
    float x = A[0] * vx + A[1] * vy + A[2]  * vz + A[3];
    float y = A[4] * vx + A[5] * vy + A[6]  * vz + A[7];
    float z = A[8] * vx + A[9] * vy + A[10] * vz + A[11];
    float p0 = (ch == 0) ? x : (ch == 1) ? y : z;
    const float* Fc = flow + ((size_t)b * 3 + ch) * (size_t)DHW;
    const float scale = (float)(1.0 / NSTEPS);
    float cc[8];
    int key = -1;
    int bl = piw * 3;
    for (int s = 0; s < NSTEPS; s++) {
        float pd = fminf(fmaxf(x, 0.0f), (float)(DIM - 1));
        float ph = fminf(fmaxf(y, 0.0f), (float)(DIM - 1));
        float pw = fminf(fmaxf(z, 0.0f), (float)(DIM - 1));
        float fd0 = floorf(pd), fh0 = floorf(ph), fw0 = floorf(pw);
        int d0 = (int)fd0, h0 = (int)fh0, w0 = (int)fw0;
        float fd = pd - fd0, fh = ph - fh0, fw = pw - fw0;
        int k = (d0 * DIM + h0) * DIM + w0;
        if (k != key) {
            key = k;
            int d1 = min(d0 + 1, DIM - 1);
            int h1 = min(h0 + 1, DIM - 1);
            int w1 = min(w0 + 1, DIM - 1);
            int r00 = (d0 * DIM + h0) * DIM;
            int r01 = (d0 * DIM + h1) * DIM;
            int r10 = (d1 * DIM + h0) * DIM;
            int r11 = (d1 * DIM + h1) * DIM;
            cc[0] = Fc[r00 + w0] * scale;
            cc[1] = Fc[r00 + w1] * scale;
            cc[2] = Fc[r01 + w0] * scale;
            cc[3] = Fc[r01 + w1] * scale;
            cc[4] = Fc[r10 + w0] * scale;
            cc[5] = Fc[r10 + w1] * scale;
            cc[6] = Fc[r11 + w0] * scale;
            cc[7] = Fc[r11 + w1] * scale;
        }
        float omfw = 1.0f - fw, omfh = 1.0f - fh, omfd = 1.0f - fd;
        float c00 = cc[0] * omfw + cc[1] * fw;
        float c01 = cc[2] * omfw + cc[3] * fw;
        float c10 = cc[4] * omfw + cc[5] * fw;
        float c11 = cc[6] * omfw + cc[7] * fw;
        float c0 = c00 * omfh + c01 * fh;
        float c1 = c10 * omfh + c11 * fh;
        float val = c0 * omfd + c1 * fd;
        float v0 = __shfl(val, bl,     64);
        float v1 = __shfl(val, bl + 1, 64);
        float v2 = __shfl(val, bl + 2, 64);
        x += v0; y += v1; z += v2;
    }
    if (valid) {
        float posc = (ch == 0) ? x : (ch == 1) ? y : z;
        float fint = posc - p0;
        const float* Ai = invaff + b * 16 + ch * 4;
        float o = Ai[0] * x + Ai[1] * y + Ai[2] * z + Ai[3];
        out_pred[(size_t)ptc * 3 + ch] = o;
        out_flow[(size_t)b * 3 * N + (size_t)ch * N + n] = fint;
    }
}

extern "C" void kernel_launch(void* const* d_in, const int* in_sizes, int n_in,
                              void* d_out, int out_size, void* d_ws, size_t ws_size,
                              hipStream_t stream) {
    const float* verts  = (const float*)d_in[0];
    const float* affine = (const float*)d_in[1];
    const float* flow   = (const float*)d_in[2];

    int B = in_sizes[1] / 16;          // affine is B*4*4
    int N = in_sizes[0] / (3 * B);     // verts is B*N*3
    int total = B * N;
    int NB = B * DIM;

    float* out_pred = (float*)d_out;                      // (B,N,3)
    float* out_flow = out_pred + (size_t)B * N * 3;       // (B,3,N)

    // ws layout: invaff | hist | cursors | order  (16B-aligned each)
    size_t off_inv  = 0;
    size_t off_hist = (off_inv + (size_t)B * 16 * 4 + 15) & ~(size_t)15;
    size_t off_cur  = (off_hist + (size_t)NB * 4 + 15) & ~(size_t)15;
    size_t off_ord  = (off_cur + (size_t)NB * 4 + 15) & ~(size_t)15;
    size_t need     = off_ord + (size_t)total * 4;
    bool use_sorted = (ws_size >= need);

    long waves  = ((long)total + PTS_PER_WAVE - 1) / PTS_PER_WAVE;
    long blocks = (waves + 3) / 4;     // 4 waves per 256-thread block

    if (use_sorted) {
        float* invaff = (float*)((char*)d_ws + off_inv);
        int* hist     = (int*)((char*)d_ws + off_hist);
        int* cursors  = (int*)((char*)d_ws + off_cur);
        int* order    = (int*)((char*)d_ws + off_ord);

        int sblocks = (total + 255) / 256;
        if (sblocks > 1024) sblocks = 1024;

        hipLaunchKernelGGL(setup_kernel, dim3(1), dim3(256), 0, stream,
                           affine, invaff, hist, NB, B);
        hipLaunchKernelGGL(hist_kernel, dim3(sblocks), dim3(256), 0, stream,
                           verts, affine, hist, N, B, total);
        hipLaunchKernelGGL(scan_kernel, dim3(1), dim3(256), 0, stream,
                           hist, cursors, NB);
        hipLaunchKernelGGL(scatter_kernel, dim3(sblocks), dim3(256), 0, stream,
                           verts, affine, cursors, order, N, B, total);
        hipLaunchKernelGGL(deform_sorted_kernel, dim3((unsigned)blocks), dim3(256),
                           0, stream, verts, affine, flow, invaff, order,
                           out_pred, out_flow, N, B);
    } else {
        float* invaff = (float*)d_ws;
        hipLaunchKernelGGL(setup_kernel, dim3(1), dim3(256), 0, stream,
                           affine, invaff, (int*)((char*)d_ws + 256), 0, B);
        hipLaunchKernelGGL(deform_kernel, dim3((unsigned)blocks), dim3(256), 0,
                           stream, verts, affine, flow, invaff,
                           out_pred, out_flow, N, B);
    }
}

// Round 4
// 367.058 us; speedup vs baseline: 1.2807x; 1.2807x over previous
//
#include <hip/hip_runtime.h>
#include <hip/hip_fp16.h>

#define NSTEPS 30
#define DIM 192
static constexpr long DHW = (long)DIM * DIM * DIM;
static constexpr int PTS_PER_WAVE = 21;   // 3 lanes per point, lane 63 idle

// Unrolled cofactor 4x4 inverse in double — registers only, no scratch.
__global__ void invert4x4_kernel(const float* __restrict__ aff,
                                 float* __restrict__ out, int B) {
    int b = blockIdx.x * blockDim.x + threadIdx.x;
    if (b >= B) return;
    double a[16];
#pragma unroll
    for (int i = 0; i < 16; i++) a[i] = (double)aff[b * 16 + i];
    double s0 = a[0]*a[5]  - a[4]*a[1];
    double s1 = a[0]*a[6]  - a[4]*a[2];
    double s2 = a[0]*a[7]  - a[4]*a[3];
    double s3 = a[1]*a[6]  - a[5]*a[2];
    double s4 = a[1]*a[7]  - a[5]*a[3];
    double s5 = a[2]*a[7]  - a[6]*a[3];
    double c5 = a[10]*a[15] - a[14]*a[11];
    double c4 = a[9]*a[15]  - a[13]*a[11];
    double c3 = a[9]*a[14]  - a[13]*a[10];
    double c2 = a[8]*a[15]  - a[12]*a[11];
    double c1 = a[8]*a[14]  - a[12]*a[10];
    double c0 = a[8]*a[13]  - a[12]*a[9];
    double det = s0*c5 - s1*c4 + s2*c3 + s3*c2 - s4*c1 + s5*c0;
    double inv = 1.0 / det;
    double o[16];
    o[0]  = ( a[5]*c5 - a[6]*c4 + a[7]*c3) * inv;
    o[1]  = (-a[1]*c5 + a[2]*c4 - a[3]*c3) * inv;
    o[2]  = ( a[13]*s5 - a[14]*s4 + a[15]*s3) * inv;
    o[3]  = (-a[9]*s5 + a[10]*s4 - a[11]*s3) * inv;
    o[4]  = (-a[4]*c5 + a[6]*c2 - a[7]*c1) * inv;
    o[5]  = ( a[0]*c5 - a[2]*c2 + a[3]*c1) * inv;
    o[6]  = (-a[12]*s5 + a[14]*s2 - a[15]*s1) * inv;
    o[7]  = ( a[8]*s5 - a[10]*s2 + a[11]*s1) * inv;
    o[8]  = ( a[4]*c4 - a[5]*c2 + a[7]*c0) * inv;
    o[9]  = (-a[0]*c4 + a[1]*c2 - a[3]*c0) * inv;
    o[10] = ( a[12]*s4 - a[13]*s2 + a[15]*s0) * inv;
    o[11] = (-a[8]*s4 + a[9]*s2 - a[11]*s0) * inv;
    o[12] = (-a[4]*c3 + a[5]*c1 - a[6]*c0) * inv;
    o[13] = ( a[0]*c3 - a[1]*c1 + a[2]*c0) * inv;
    o[14] = (-a[12]*s3 + a[13]*s1 - a[14]*s0) * inv;
    o[15] = ( a[8]*s3 - a[9]*s1 + a[10]*s0) * inv;
#pragma unroll
    for (int i = 0; i < 16; i++) out[b * 16 + i] = (float)o[i];
}

// Repack flow (B,3,D,H,W) f32 -> (B,3,D,H,W) fp16 PLANAR. The 3-lane deform
// reads only its own channel, so no interleaving needed: 85 MB instead of
// 113 MB (r0's x4-interleave) -> less write BW + better L3 residency.
// 2 voxels/thread: float2 reads x3, __half2 stores x3.
__global__ __launch_bounds__(256) void repack_kernel(
    const float* __restrict__ flow, __half* __restrict__ packed) {
    long vox2 = (long)blockIdx.x * blockDim.x + threadIdx.x;  // voxel-pair idx
    int b = blockIdx.y;
    if (vox2 >= DHW / 2) return;
    long vox = vox2 * 2;
    const float* F = flow + (size_t)b * 3 * DHW;
    __half* P = packed + (size_t)b * 3 * DHW;
#pragma unroll
    for (int c = 0; c < 3; c++) {
        float2 f = *reinterpret_cast<const float2*>(F + (size_t)c * DHW + vox);
        *reinterpret_cast<__half2*>(P + (size_t)c * DHW + vox) =
            __floats2half2_rn(f.x, f.y);
    }
}

// 3 lanes per point, gathering from the planar fp16 volume. 280k pts / 21
// per wave = 13334 waves -> 8 waves/SIMD, which hides the per-step gather
// latency (r1's 1-lane variant at 4.3 waves/SIMD regressed +16us). The
// packed volume is freshly written each iteration -> L3-resident -> gathers
// are L3 hits (deform never appears in rocprof top-5).
__global__ __launch_bounds__(256) void deform_packed_kernel(
    const float* __restrict__ verts,
    const float* __restrict__ affine,
    const __half* __restrict__ packed,
    const float* __restrict__ invaff,
    float* __restrict__ out_pred,
    float* __restrict__ out_flow,
    int N, int B) {
    int lane = threadIdx.x & 63;
    int wib  = threadIdx.x >> 6;
    long gwave = (long)blockIdx.x * (blockDim.x >> 6) + wib;

    int piw = lane / 3;
    if (piw > PTS_PER_WAVE - 1) piw = PTS_PER_WAVE - 1;
    int ch = lane - piw * 3;
    if (ch > 2) ch = 2;

    long pt = gwave * PTS_PER_WAVE + piw;
    bool valid = (lane < 63) && (pt < (long)B * N);
    long ptc = valid ? pt : ((long)B * N - 1);
    int b = (int)(ptc / N);
    int n = (int)(ptc - (long)b * N);

    const float* A = affine + b * 16;
    const float* v = verts + (size_t)ptc * 3;
    float vx = v[0], vy = v[1], vz = v[2];
    float x = A[0] * vx + A[1] * vy + A[2]  * vz + A[3];
    float y = A[4] * vx + A[5] * vy + A[6]  * vz + A[7];
    float z = A[8] * vx + A[9] * vy + A[10] * vz + A[11];
    float p0 = (ch == 0) ? x : (ch == 1) ? y : z;

    // own-channel plane base (units: halves)
    const __half* Pb = packed + ((size_t)b * 3 + ch) * (size_t)DHW;
    const float scale = (float)(1.0 / NSTEPS);

    float cc[8];
    int key = -1;
    int bl = piw * 3;

    for (int s = 0; s < NSTEPS; s++) {
        float pd = fminf(fmaxf(x, 0.0f), (float)(DIM - 1));
        float ph = fminf(fmaxf(y, 0.0f), (float)(DIM - 1));
        float pw = fminf(fmaxf(z, 0.0f), (float)(DIM - 1));
        float fd0 = floorf(pd), fh0 = floorf(ph), fw0 = floorf(pw);
        int d0 = (int)fd0, h0 = (int)fh0, w0 = (int)fw0;
        float fd = pd - fd0, fh = ph - fh0, fw = pw - fw0;

        int k = (d0 * DIM + h0) * DIM + w0;
        if (k != key) {
            key = k;
            int d1 = min(d0 + 1, DIM - 1);
            int h1 = min(h0 + 1, DIM - 1);
            int w1 = min(w0 + 1, DIM - 1);
            int r00 = (d0 * DIM + h0) * DIM;
            int r01 = (d0 * DIM + h1) * DIM;
            int r10 = (d1 * DIM + h0) * DIM;
            int r11 = (d1 * DIM + h1) * DIM;
            cc[0] = __half2float(Pb[r00 + w0]) * scale;
            cc[1] = __half2float(Pb[r00 + w1]) * scale;
            cc[2] = __half2float(Pb[r01 + w0]) * scale;
            cc[3] = __half2float(Pb[r01 + w1]) * scale;
            cc[4] = __half2float(Pb[r10 + w0]) * scale;
            cc[5] = __half2float(Pb[r10 + w1]) * scale;
            cc[6] = __half2float(Pb[r11 + w0]) * scale;
            cc[7] = __half2float(Pb[r11 + w1]) * scale;
        }

        float omfw = 1.0f - fw, omfh = 1.0f - fh, omfd = 1.0f - fd;
        float c00 = cc[0] * omfw + cc[1] * fw;
        float c01 = cc[2] * omfw + cc[3] * fw;
        float c10 = cc[4] * omfw + cc[5] * fw;
        float c11 = cc[6] * omfw + cc[7] * fw;
        float c0 = c00 * omfh + c01 * fh;
        float c1 = c10 * omfh + c11 * fh;
        float val = c0 * omfd + c1 * fd;

        float v0 = __shfl(val, bl,     64);
        float v1 = __shfl(val, bl + 1, 64);
        float v2 = __shfl(val, bl + 2, 64);
        x += v0; y += v1; z += v2;
    }

    if (valid) {
        float posc = (ch == 0) ? x : (ch == 1) ? y : z;
        float fint = posc - p0;
        const float* Ai = invaff + b * 16 + ch * 4;
        float o = Ai[0] * x + Ai[1] * y + Ai[2] * z + Ai[3];
        out_pred[(size_t)ptc * 3 + ch] = o;
        out_flow[(size_t)b * 3 * N + (size_t)ch * N + n] = fint;
    }
}

// Fallback: f32 direct-gather kernel (used only if ws too small).
__global__ __launch_bounds__(256) void deform_kernel(
    const float* __restrict__ verts,
    const float* __restrict__ affine,
    const float* __restrict__ flow,
    const float* __restrict__ invaff,
    float* __restrict__ out_pred,
    float* __restrict__ out_flow,
    int N, int B) {
    int lane = threadIdx.x & 63;
    int wib  = threadIdx.x >> 6;
    long gwave = (long)blockIdx.x * (blockDim.x >> 6) + wib;
    int piw = lane / 3;
    if (piw > PTS_PER_WAVE - 1) piw = PTS_PER_WAVE - 1;
    int ch = lane - piw * 3;
    if (ch > 2) ch = 2;
    long pt = gwave * PTS_PER_WAVE + piw;
    bool valid = (lane < 63) && (pt < (long)B * N);
    long ptc = valid ? pt : ((long)B * N - 1);
    int b = (int)(ptc / N);
    int n = (int)(ptc - (long)b * N);
    const float* A = affine + b * 16;
    const float* v = verts + (size_t)ptc * 3;
    float vx = v[0], vy = v[1], vz = v[2];
    float x = A[0] * vx + A[1] * vy + A[2]  * vz + A[3];
    float y = A[4] * vx + A[5] * vy + A[6]  * vz + A[7];
    float z = A[8] * vx + A[9] * vy + A[10] * vz + A[11];
    float p0 = (ch == 0) ? x : (ch == 1) ? y : z;
    const float* Fc = flow + ((size_t)b * 3 + ch) * (size_t)DHW;
    const float scale = (float)(1.0 / NSTEPS);
    float cc[8];
    int key = -1;
    int bl = piw * 3;
    for (int s = 0; s < NSTEPS; s++) {
        float pd = fminf(fmaxf(x, 0.0f), (float)(DIM - 1));
        float ph = fminf(fmaxf(y, 0.0f), (float)(DIM - 1));
        float pw = fminf(fmaxf(z, 0.0f), (float)(DIM - 1));
        float fd0 = floorf(pd), fh0 = floorf(ph), fw0 = floorf(pw);
        int d0 = (int)fd0, h0 = (int)fh0, w0 = (int)fw0;
        float fd = pd - fd0, fh = ph - fh0, fw = pw - fw0;
        int k = (d0 * DIM + h0) * DIM + w0;
        if (k != key) {
            key = k;
            int d1 = min(d0 + 1, DIM - 1);
            int h1 = min(h0 + 1, DIM - 1);
            int w1 = min(w0 + 1, DIM - 1);
            int r00 = (d0 * DIM + h0) * DIM;
            int r01 = (d0 * DIM + h1) * DIM;
            int r10 = (d1 * DIM + h0) * DIM;
            int r11 = (d1 * DIM + h1) * DIM;
            cc[0] = Fc[r00 + w0] * scale;
            cc[1] = Fc[r00 + w1] * scale;
            cc[2] = Fc[r01 + w0] * scale;
            cc[3] = Fc[r01 + w1] * scale;
            cc[4] = Fc[r10 + w0] * scale;
            cc[5] = Fc[r10 + w1] * scale;
            cc[6] = Fc[r11 + w0] * scale;
            cc[7] = Fc[r11 + w1] * scale;
        }
        float omfw = 1.0f - fw, omfh = 1.0f - fh, omfd = 1.0f - fd;
        float c00 = cc[0] * omfw + cc[1] * fw;
        float c01 = cc[2] * omfw + cc[3] * fw;
        float c10 = cc[4] * omfw + cc[5] * fw;
        float c11 = cc[6] * omfw + cc[7] * fw;
        float c0 = c00 * omfh + c01 * fh;
        float c1 = c10 * omfh + c11 * fh;
        float val = c0 * omfd + c1 * fd;
        float v0 = __shfl(val, bl,     64);
        float v1 = __shfl(val, bl + 1, 64);
        float v2 = __shfl(val, bl + 2, 64);
        x += v0; y += v1; z += v2;
    }
    if (valid) {
        float posc = (ch == 0) ? x : (ch == 1) ? y : z;
        float fint = posc - p0;
        const float* Ai = invaff + b * 16 + ch * 4;
        float o = Ai[0] * x + Ai[1] * y + Ai[2] * z + Ai[3];
        out_pred[(size_t)ptc * 3 + ch] = o;
        out_flow[(size_t)b * 3 * N + (size_t)ch * N + n] = fint;
    }
}

extern "C" void kernel_launch(void* const* d_in, const int* in_sizes, int n_in,
                              void* d_out, int out_size, void* d_ws, size_t ws_size,
                              hipStream_t stream) {
    const float* verts  = (const float*)d_in[0];
    const float* affine = (const float*)d_in[1];
    const float* flow   = (const float*)d_in[2];

    int B = in_sizes[1] / 16;          // affine is B*4*4
    int N = in_sizes[0] / (3 * B);     // verts is B*N*3

    float* out_pred = (float*)d_out;                      // (B,N,3)
    float* out_flow = out_pred + (size_t)B * N * 3;       // (B,3,N)

    size_t packed_bytes = (size_t)B * 3 * DHW * sizeof(__half);  // 6B/voxel planar
    bool use_packed = (ws_size >= packed_bytes + 256);

    long total_pts = (long)B * N;
    long waves  = (total_pts + PTS_PER_WAVE - 1) / PTS_PER_WAVE;
    long blocks = (waves + 3) / 4;     // 4 waves per 256-thread block

    if (use_packed) {
        __half* packed = (__half*)d_ws;
        float* invaff  = (float*)((char*)d_ws + packed_bytes);
        hipLaunchKernelGGL(invert4x4_kernel, dim3(1), dim3(64), 0, stream,
                           affine, invaff, B);
        long vblocks = (DHW / 2 + 255) / 256;
        hipLaunchKernelGGL(repack_kernel, dim3((unsigned)vblocks, B), dim3(256), 0,
                           stream, flow, packed);
        hipLaunchKernelGGL(deform_packed_kernel, dim3((unsigned)blocks), dim3(256),
                           0, stream, verts, affine, packed, invaff,
                           out_pred, out_flow, N, B);
    } else {
        float* invaff = (float*)d_ws;
        hipLaunchKernelGGL(invert4x4_kernel, dim3(1), dim3(64), 0, stream,
                           affine, invaff, B);
        hipLaunchKernelGGL(deform_kernel, dim3((unsigned)blocks), dim3(256), 0,
                           stream, verts, affine, flow, invaff,
                           out_pred, out_flow, N, B);
    }
}

// Round 5
// 304.997 us; speedup vs baseline: 1.5413x; 1.2035x over previous
//
#include <hip/hip_runtime.h>
#include <hip/hip_fp16.h>

#define NSTEPS 30
#define DIM 192
static constexpr long DHW = (long)DIM * DIM * DIM;
static constexpr int PTS_PER_WAVE = 21;   // 3 lanes per point, lane 63 idle

// Unrolled cofactor 4x4 inverse in double — registers only, no scratch.
__global__ void invert4x4_kernel(const float* __restrict__ aff,
                                 float* __restrict__ out, int B) {
    int b = blockIdx.x * blockDim.x + threadIdx.x;
    if (b >= B) return;
    double a[16];
#pragma unroll
    for (int i = 0; i < 16; i++) a[i] = (double)aff[b * 16 + i];
    double s0 = a[0]*a[5]  - a[4]*a[1];
    double s1 = a[0]*a[6]  - a[4]*a[2];
    double s2 = a[0]*a[7]  - a[4]*a[3];
    double s3 = a[1]*a[6]  - a[5]*a[2];
    double s4 = a[1]*a[7]  - a[5]*a[3];
    double s5 = a[2]*a[7]  - a[6]*a[3];
    double c5 = a[10]*a[15] - a[14]*a[11];
    double c4 = a[9]*a[15]  - a[13]*a[11];
    double c3 = a[9]*a[14]  - a[13]*a[10];
    double c2 = a[8]*a[15]  - a[12]*a[11];
    double c1 = a[8]*a[14]  - a[12]*a[10];
    double c0 = a[8]*a[13]  - a[12]*a[9];
    double det = s0*c5 - s1*c4 + s2*c3 + s3*c2 - s4*c1 + s5*c0;
    double inv = 1.0 / det;
    double o[16];
    o[0]  = ( a[5]*c5 - a[6]*c4 + a[7]*c3) * inv;
    o[1]  = (-a[1]*c5 + a[2]*c4 - a[3]*c3) * inv;
    o[2]  = ( a[13]*s5 - a[14]*s4 + a[15]*s3) * inv;
    o[3]  = (-a[9]*s5 + a[10]*s4 - a[11]*s3) * inv;
    o[4]  = (-a[4]*c5 + a[6]*c2 - a[7]*c1) * inv;
    o[5]  = ( a[0]*c5 - a[2]*c2 + a[3]*c1) * inv;
    o[6]  = (-a[12]*s5 + a[14]*s2 - a[15]*s1) * inv;
    o[7]  = ( a[8]*s5 - a[10]*s2 + a[11]*s1) * inv;
    o[8]  = ( a[4]*c4 - a[5]*c2 + a[7]*c0) * inv;
    o[9]  = (-a[0]*c4 + a[1]*c2 - a[3]*c0) * inv;
    o[10] = ( a[12]*s4 - a[13]*s2 + a[15]*s0) * inv;
    o[11] = (-a[8]*s4 + a[9]*s2 - a[11]*s0) * inv;
    o[12] = (-a[4]*c3 + a[5]*c1 - a[6]*c0) * inv;
    o[13] = ( a[0]*c3 - a[1]*c1 + a[2]*c0) * inv;
    o[14] = (-a[12]*s3 + a[13]*s1 - a[14]*s0) * inv;
    o[15] = ( a[8]*s3 - a[9]*s1 + a[10]*s0) * inv;
#pragma unroll
    for (int i = 0; i < 16; i++) out[b * 16 + i] = (float)o[i];
}

// Repack flow (B,3,D,H,W) f32 -> (B,D,H,W,3) fp16 interleaved, 6B/voxel.
// Channel interleaving is the load-bearing optimization (r4 post-mortem):
// the 3 lanes of a point read 3 consecutive halves -> one 64B line instead
// of 3. x3 (85 MB) vs r0's x4 (113 MB) drops 28 MB of write BW and shrinks
// the L3 footprint. 2 voxels/thread: 3 x float2 reads, 3 x int stores
// (12B per pair, 4B-aligned), fully coalesced.
__global__ __launch_bounds__(256) void repack_kernel(
    const float* __restrict__ flow, __half* __restrict__ packed) {
    long vox2 = (long)blockIdx.x * blockDim.x + threadIdx.x;  // voxel-pair idx
    int b = blockIdx.y;
    if (vox2 >= DHW / 2) return;
    long vox = vox2 * 2;
    const float* F = flow + (size_t)b * 3 * DHW;
    float2 f0 = *reinterpret_cast<const float2*>(F + vox);            // ch0: v0,v1
    float2 f1 = *reinterpret_cast<const float2*>(F + DHW + vox);      // ch1
    float2 f2 = *reinterpret_cast<const float2*>(F + 2 * DHW + vox);  // ch2
    union { __half2 h2[3]; int i[3]; } u;
    // layout per pair: [v0c0 v0c1][v0c2 v1c0][v1c1 v1c2]
    u.h2[0] = __floats2half2_rn(f0.x, f1.x);
    u.h2[1] = __floats2half2_rn(f2.x, f0.y);
    u.h2[2] = __floats2half2_rn(f1.y, f2.y);
    int* dst = reinterpret_cast<int*>((char*)packed +
                                      ((size_t)b * 3 * DHW + (size_t)vox * 3) * 2);
    dst[0] = u.i[0];
    dst[1] = u.i[1];
    dst[2] = u.i[2];
}

// 3 lanes per point, gathering from the x3-interleaved fp16 volume.
// 280k pts / 21 per wave = 13334 waves -> 8 waves/SIMD residency (hides the
// per-step gather latency; r1's 1-lane variant at 4.3 waves/SIMD regressed).
// The packed volume is freshly written each iteration -> L3-resident ->
// gathers are L3 hits and deform stays out of the rocprof top-5.
__global__ __launch_bounds__(256) void deform_packed_kernel(
    const float* __restrict__ verts,
    const float* __restrict__ affine,
    const __half* __restrict__ packed,
    const float* __restrict__ invaff,
    float* __restrict__ out_pred,
    float* __restrict__ out_flow,
    int N, int B) {
    int lane = threadIdx.x & 63;
    int wib  = threadIdx.x >> 6;
    long gwave = (long)blockIdx.x * (blockDim.x >> 6) + wib;

    int piw = lane / 3;
    if (piw > PTS_PER_WAVE - 1) piw = PTS_PER_WAVE - 1;
    int ch = lane - piw * 3;
    if (ch > 2) ch = 2;

    long pt = gwave * PTS_PER_WAVE + piw;
    bool valid = (lane < 63) && (pt < (long)B * N);
    long ptc = valid ? pt : ((long)B * N - 1);
    int b = (int)(ptc / N);
    int n = (int)(ptc - (long)b * N);

    const float* A = affine + b * 16;
    const float* v = verts + (size_t)ptc * 3;
    float vx = v[0], vy = v[1], vz = v[2];
    float x = A[0] * vx + A[1] * vy + A[2]  * vz + A[3];
    float y = A[4] * vx + A[5] * vy + A[6]  * vz + A[7];
    float z = A[8] * vx + A[9] * vy + A[10] * vz + A[11];
    float p0 = (ch == 0) ? x : (ch == 1) ? y : z;

    // own-channel base into the x3-interleaved volume (units: halves)
    const __half* Pb = packed + (size_t)b * 3 * DHW + ch;
    const float scale = (float)(1.0 / NSTEPS);

    float cc[8];
    int key = -1;
    int bl = piw * 3;

    for (int s = 0; s < NSTEPS; s++) {
        float pd = fminf(fmaxf(x, 0.0f), (float)(DIM - 1));
        float ph = fminf(fmaxf(y, 0.0f), (float)(DIM - 1));
        float pw = fminf(fmaxf(z, 0.0f), (float)(DIM - 1));
        float fd0 = floorf(pd), fh0 = floorf(ph), fw0 = floorf(pw);
        int d0 = (int)fd0, h0 = (int)fh0, w0 = (int)fw0;
        float fd = pd - fd0, fh = ph - fh0, fw = pw - fw0;

        int k = (d0 * DIM + h0) * DIM + w0;
        if (k != key) {
            key = k;
            int d1 = min(d0 + 1, DIM - 1);
            int h1 = min(h0 + 1, DIM - 1);
            int w1 = min(w0 + 1, DIM - 1);
            size_t r00 = (size_t)((d0 * DIM + h0) * DIM) * 3;
            size_t r01 = (size_t)((d0 * DIM + h1) * DIM) * 3;
            size_t r10 = (size_t)((d1 * DIM + h0) * DIM) * 3;
            size_t r11 = (size_t)((d1 * DIM + h1) * DIM) * 3;
            size_t o0 = (size_t)w0 * 3, o1 = (size_t)w1 * 3;
            cc[0] = __half2float(Pb[r00 + o0]) * scale;
            cc[1] = __half2float(Pb[r00 + o1]) * scale;
            cc[2] = __half2float(Pb[r01 + o0]) * scale;
            cc[3] = __half2float(Pb[r01 + o1]) * scale;
            cc[4] = __half2float(Pb[r10 + o0]) * scale;
            cc[5] = __half2float(Pb[r10 + o1]) * scale;
            cc[6] = __half2float(Pb[r11 + o0]) * scale;
            cc[7] = __half2float(Pb[r11 + o1]) * scale;
        }

        float omfw = 1.0f - fw, omfh = 1.0f - fh, omfd = 1.0f - fd;
        float c00 = cc[0] * omfw + cc[1] * fw;
        float c01 = cc[2] * omfw + cc[3] * fw;
        float c10 = cc[4] * omfw + cc[5] * fw;
        float c11 = cc[6] * omfw + cc[7] * fw;
        float c0 = c00 * omfh + c01 * fh;
        float c1 = c10 * omfh + c11 * fh;
        float val = c0 * omfd + c1 * fd;

        float v0 = __shfl(val, bl,     64);
        float v1 = __shfl(val, bl + 1, 64);
        float v2 = __shfl(val, bl + 2, 64);
        x += v0; y += v1; z += v2;
    }

    if (valid) {
        float posc = (ch == 0) ? x : (ch == 1) ? y : z;
        float fint = posc - p0;
        const float* Ai = invaff + b * 16 + ch * 4;
        float o = Ai[0] * x + Ai[1] * y + Ai[2] * z + Ai[3];
        out_pred[(size_t)ptc * 3 + ch] = o;
        out_flow[(size_t)b * 3 * N + (size_t)ch * N + n] = fint;
    }
}

// Fallback: f32 direct-gather kernel (used only if ws too small).
__global__ __launch_bounds__(256) void deform_kernel(
    const float* __restrict__ verts,
    const float* __restrict__ affine,
    const float* __restrict__ flow,
    const float* __restrict__ invaff,
    float* __restrict__ out_pred,
    float* __restrict__ out_flow,
    int N, int B) {
    int lane = threadIdx.x & 63;
    int wib  = threadIdx.x >> 6;
    long gwave = (long)blockIdx.x * (blockDim.x >> 6) + wib;
    int piw = lane / 3;
    if (piw > PTS_PER_WAVE - 1) piw = PTS_PER_WAVE - 1;
    int ch = lane - piw * 3;
    if (ch > 2) ch = 2;
    long pt = gwave * PTS_PER_WAVE + piw;
    bool valid = (lane < 63) && (pt < (long)B * N);
    long ptc = valid ? pt : ((long)B * N - 1);
    int b = (int)(ptc / N);
    int n = (int)(ptc - (long)b * N);
    const float* A = affine + b * 16;
    const float* v = verts + (size_t)ptc * 3;
    float vx = v[0], vy = v[1], vz = v[2];
    float x = A[0] * vx + A[1] * vy + A[2]  * vz + A[3];
    float y = A[4] * vx + A[5] * vy + A[6]  * vz + A[7];
    float z = A[8] * vx + A[9] * vy + A[10] * vz + A[11];
    float p0 = (ch == 0) ? x : (ch == 1) ? y : z;
    const float* Fc = flow + ((size_t)b * 3 + ch) * (size_t)DHW;
    const float scale = (float)(1.0 / NSTEPS);
    float cc[8];
    int key = -1;
    int bl = piw * 3;
    for (int s = 0; s < NSTEPS; s++) {
        float pd = fminf(fmaxf(x, 0.0f), (float)(DIM - 1));
        float ph = fminf(fmaxf(y, 0.0f), (float)(DIM - 1));
        float pw = fminf(fmaxf(z, 0.0f), (float)(DIM - 1));
        float fd0 = floorf(pd), fh0 = floorf(ph), fw0 = floorf(pw);
        int d0 = (int)fd0, h0 = (int)fh0, w0 = (int)fw0;
        float fd = pd - fd0, fh = ph - fh0, fw = pw - fw0;
        int k = (d0 * DIM + h0) * DIM + w0;
        if (k != key) {
            key = k;
            int d1 = min(d0 + 1, DIM - 1);
            int h1 = min(h0 + 1, DIM - 1);
            int w1 = min(w0 + 1, DIM - 1);
            int r00 = (d0 * DIM + h0) * DIM;
            int r01 = (d0 * DIM + h1) * DIM;
            int r10 = (d1 * DIM + h0) * DIM;
            int r11 = (d1 * DIM + h1) * DIM;
            cc[0] = Fc[r00 + w0] * scale;
            cc[1] = Fc[r00 + w1] * scale;
            cc[2] = Fc[r01 + w0] * scale;
            cc[3] = Fc[r01 + w1] * scale;
            cc[4] = Fc[r10 + w0] * scale;
            cc[5] = Fc[r10 + w1] * scale;
            cc[6] = Fc[r11 + w0] * scale;
            cc[7] = Fc[r11 + w1] * scale;
        }
        float omfw = 1.0f - fw, omfh = 1.0f - fh, omfd = 1.0f - fd;
        float c00 = cc[0] * omfw + cc[1] * fw;
        float c01 = cc[2] * omfw + cc[3] * fw;
        float c10 = cc[4] * omfw + cc[5] * fw;
        float c11 = cc[6] * omfw + cc[7] * fw;
        float c0 = c00 * omfh + c01 * fh;
        float c1 = c10 * omfh + c11 * fh;
        float val = c0 * omfd + c1 * fd;
        float v0 = __shfl(val, bl,     64);
        float v1 = __shfl(val, bl + 1, 64);
        float v2 = __shfl(val, bl + 2, 64);
        x += v0; y += v1; z += v2;
    }
    if (valid) {
        float posc = (ch == 0) ? x : (ch == 1) ? y : z;
        float fint = posc - p0;
        const float* Ai = invaff + b * 16 + ch * 4;
        float o = Ai[0] * x + Ai[1] * y + Ai[2] * z + Ai[3];
        out_pred[(size_t)ptc * 3 + ch] = o;
        out_flow[(size_t)b * 3 * N + (size_t)ch * N + n] = fint;
    }
}

extern "C" void kernel_launch(void* const* d_in, const int* in_sizes, int n_in,
                              void* d_out, int out_size, void* d_ws, size_t ws_size,
                              hipStream_t stream) {
    const float* verts  = (const float*)d_in[0];
    const float* affine = (const float*)d_in[1];
    const float* flow   = (const float*)d_in[2];

    int B = in_sizes[1] / 16;          // affine is B*4*4
    int N = in_sizes[0] / (3 * B);     // verts is B*N*3

    float* out_pred = (float*)d_out;                      // (B,N,3)
    float* out_flow = out_pred + (size_t)B * N * 3;       // (B,3,N)

    size_t packed_bytes = (size_t)B * 3 * DHW * sizeof(__half);  // 6B/voxel
    bool use_packed = (ws_size >= packed_bytes + 256);

    long total_pts = (long)B * N;
    long waves  = (total_pts + PTS_PER_WAVE - 1) / PTS_PER_WAVE;
    long blocks = (waves + 3) / 4;     // 4 waves per 256-thread block

    if (use_packed) {
        __half* packed = (__half*)d_ws;
        float* invaff  = (float*)((char*)d_ws + packed_bytes);
        hipLaunchKernelGGL(invert4x4_kernel, dim3(1), dim3(64), 0, stream,
                           affine, invaff, B);
        long vblocks = (DHW / 2 + 255) / 256;
        hipLaunchKernelGGL(repack_kernel, dim3((unsigned)vblocks, B), dim3(256), 0,
                           stream, flow, packed);
        hipLaunchKernelGGL(deform_packed_kernel, dim3((unsigned)blocks), dim3(256),
                           0, stream, verts, affine, packed, invaff,
                           out_pred, out_flow, N, B);
    } else {
        float* invaff = (float*)d_ws;
        hipLaunchKernelGGL(invert4x4_kernel, dim3(1), dim3(64), 0, stream,
                           affine, invaff, B);
        hipLaunchKernelGGL(deform_kernel, dim3((unsigned)blocks), dim3(256), 0,
                           stream, verts, affine, flow, invaff,
                           out_pred, out_flow, N, B);
    }
}